// Round 7
// baseline (1043.187 us; speedup 1.0000x reference)
//
#include <hip/hip_runtime.h>

// LaplaceMeshLoss: COO Laplacian SpMV + per-row norm + weighted scalar reduce.
//
// R12: row-sort + register accumulation (atomic-free accumulate).
//   Established facts (R6/R8/R9/R11): bucket accumulate is ~312us INVARIANT
//   to fetch bytes (848/730/201MB) and ILP -> not memory-locality-bound.
//   Remaining suspects: DS-unit occupancy of 4 wave64 LDS atomics/entry, or
//   divergent-VMEM issue. This round removes the LDS atomics:
//   - drop segment resort + barrier machinery (R11: locality is immaterial);
//   - new fused rowsort_accum_kernel per bucket: count rows in LDS (1 atomic/
//     entry) -> LDS scan -> place row-sorted into global entries2 (1 atomic +
//     8B write/entry) -> __syncthreads -> each thread owns 4 consecutive rows,
//     reads its contiguous runs, gathers verts4 (same divergence as before),
//     accumulates in REGISTERS (0 atomics), finalizes in place.
//   Discriminator: if accumulate phase stays ~300us -> divergent gather issue
//   is the wall; if it drops -> DS atomics were.
//
// ws layout:
//   [0,8)          double partial
//   [8,24)         int nvpm[4]
//   [24,40)        int bnd[4]       (mesh boundaries lb(1..4))
//   [64,8260)      uint bucket_base[BMAX+1]
//   [16384,24576)  uint total[BMAX]
//   [262144,+4MB)  ushort hist[BMAX*NB]
//   [+112MB)       uint2 entries[NNZ]
//   [+112MB)       uint2 entries2[NNZ]        (rowsort path only)
//   [+16V)         float4 verts4[V]

#define NB 1024           // blocks in hist/scatter phases
#define BMAX 2048         // max buckets
#define BROWS 2048        // rows per bucket (11 bits)

typedef unsigned int uintv2 __attribute__((ext_vector_type(2)));

__global__ void hist_kernel(const int* __restrict__ rows, int nnz, int cpb,
                            int B, unsigned short* __restrict__ hist,
                            const float* __restrict__ verts, int V,
                            float4* __restrict__ verts4) {
    if (verts4) {
        int stride = gridDim.x * blockDim.x;
        for (int vtx = blockIdx.x * blockDim.x + threadIdx.x; vtx < V;
             vtx += stride) {
            verts4[vtx] = make_float4(verts[3 * vtx + 0], verts[3 * vtx + 1],
                                      verts[3 * vtx + 2], 0.f);
        }
    }
    __shared__ unsigned h[BMAX];
    for (int b = threadIdx.x; b < B; b += blockDim.x) h[b] = 0;
    __syncthreads();
    int k = blockIdx.x;
    int i0 = k * cpb;
    int i1 = min(i0 + cpb, nnz);
    for (int i = i0 + 4 * (int)threadIdx.x; i < i1; i += 4 * blockDim.x) {
        if (i + 3 < i1) {
            int4 r4 = *(const int4*)(rows + i);
            atomicAdd(&h[r4.x >> 11], 1u);
            atomicAdd(&h[r4.y >> 11], 1u);
            atomicAdd(&h[r4.z >> 11], 1u);
            atomicAdd(&h[r4.w >> 11], 1u);
        } else {
            for (int j = i; j < i1; ++j) atomicAdd(&h[rows[j] >> 11], 1u);
        }
    }
    __syncthreads();
    for (int b = threadIdx.x; b < B; b += blockDim.x)
        hist[(size_t)b * NB + k] = (unsigned short)h[b];
}

__global__ void scan_blocks_kernel(unsigned short* __restrict__ hist,
                                   unsigned* __restrict__ total) {
    int b = blockIdx.x;
    int t = threadIdx.x;            // 256 threads
    int lane = t & 63, wave = t >> 6;
    unsigned short* hp = hist + (size_t)b * NB;
    ushort4 hv = ((const ushort4*)hp)[t];
    unsigned a0 = hv.x, a1 = hv.y, a2 = hv.z, a3 = hv.w;
    unsigned sum = a0 + a1 + a2 + a3;
    unsigned x = sum;
    for (int off = 1; off < 64; off <<= 1) {
        unsigned y = __shfl_up(x, off);
        if (lane >= off) x += y;
    }
    __shared__ unsigned wsum[4];
    if (lane == 63) wsum[wave] = x;
    __syncthreads();
    unsigned woff = 0;
    for (int w = 0; w < wave; ++w) woff += wsum[w];
    unsigned excl = woff + x - sum;
    ushort4 ov;
    ov.x = (unsigned short)excl;
    ov.y = (unsigned short)(excl + a0);
    ov.z = (unsigned short)(excl + a0 + a1);
    ov.w = (unsigned short)(excl + a0 + a1 + a2);
    ((ushort4*)hp)[t] = ov;
    if (t == 255) total[b] = woff + x;
}

__global__ void scan_buckets_kernel(const unsigned* __restrict__ total,
                                    unsigned* __restrict__ base, int B,
                                    const int* __restrict__ mesh_idx, int v,
                                    int* __restrict__ nvpm,
                                    int* __restrict__ bnd) {
    int t = threadIdx.x;            // 1024 threads, 2 elems each
    if (t < 4) {
        auto lb = [&](int tgt) {
            int lo = 0, hi = v;
            while (lo < hi) {
                int mid = (lo + hi) >> 1;
                if (mesh_idx[mid] < tgt) lo = mid + 1; else hi = mid;
            }
            return lo;
        };
        int hi_b = lb(t + 1);
        nvpm[t] = hi_b - lb(t);
        bnd[t]  = hi_b;
    }
    __shared__ unsigned buf0[1024], buf1[1024];
    unsigned x0 = (2 * t < B) ? total[2 * t] : 0u;
    unsigned x1 = (2 * t + 1 < B) ? total[2 * t + 1] : 0u;
    unsigned pair = x0 + x1;
    buf0[t] = pair;
    __syncthreads();
    unsigned* src = buf0;
    unsigned* dst = buf1;
    unsigned vv = pair;
    for (int off = 1; off < 1024; off <<= 1) {
        vv = src[t];
        if (t >= off) vv += src[t - off];
        dst[t] = vv;
        __syncthreads();
        unsigned* tmp = src; src = dst; dst = tmp;
    }
    unsigned excl = vv - pair;
    base[2 * t] = excl;
    base[2 * t + 1] = excl + x0;
    if (t == 1023) base[2048] = vv;
}

__global__ void scatter_kernel(const int* __restrict__ rows,
                               const int* __restrict__ cols,
                               const float* __restrict__ vals,
                               const unsigned short* __restrict__ hist,
                               const unsigned* __restrict__ base,
                               uint2* __restrict__ dst,
                               int nnz, int cpb, int B) {
    __shared__ unsigned cur[BMAX];
    int k = blockIdx.x;
    for (int b = threadIdx.x; b < B; b += blockDim.x)
        cur[b] = base[b] + hist[(size_t)b * NB + k];
    __syncthreads();
    int i0 = k * cpb;
    int i1 = min(i0 + cpb, nnz);
    for (int i = i0 + 4 * (int)threadIdx.x; i < i1; i += 4 * blockDim.x) {
        if (i + 3 < i1) {
            int4   r4 = *(const int4*)(rows + i);
            int4   c4 = *(const int4*)(cols + i);
            float4 v4 = *(const float4*)(vals + i);
            unsigned p0 = atomicAdd(&cur[r4.x >> 11], 1u);
            unsigned p1 = atomicAdd(&cur[r4.y >> 11], 1u);
            unsigned p2 = atomicAdd(&cur[r4.z >> 11], 1u);
            unsigned p3 = atomicAdd(&cur[r4.w >> 11], 1u);
            uint2 e0, e1, e2, e3;
            e0.x = ((unsigned)(r4.x & (BROWS - 1)) << 21) | (unsigned)c4.x;
            e0.y = __float_as_uint(v4.x);
            e1.x = ((unsigned)(r4.y & (BROWS - 1)) << 21) | (unsigned)c4.y;
            e1.y = __float_as_uint(v4.y);
            e2.x = ((unsigned)(r4.z & (BROWS - 1)) << 21) | (unsigned)c4.z;
            e2.y = __float_as_uint(v4.z);
            e3.x = ((unsigned)(r4.w & (BROWS - 1)) << 21) | (unsigned)c4.w;
            e3.y = __float_as_uint(v4.w);
            dst[p0] = e0;
            dst[p1] = e1;
            dst[p2] = e2;
            dst[p3] = e3;
        } else {
            for (int j = i; j < i1; ++j) {
                int r = rows[j];
                unsigned p = atomicAdd(&cur[r >> 11], 1u);
                uint2 e;
                e.x = ((unsigned)(r & (BROWS - 1)) << 21) | (unsigned)cols[j];
                e.y = __float_as_uint(vals[j]);
                dst[p] = e;
            }
        }
    }
}

// One block (512 thr) per bucket: in-LDS row counting sort -> row-sorted
// entries2 (global) -> per-thread register accumulation over 4 owned rows ->
// fused finalize. ZERO atomics in the accumulate/finalize phase.
__global__ void __launch_bounds__(512)
rowsort_accum_kernel(const uint2* __restrict__ entries,
                     const unsigned* __restrict__ base,
                     uint2* __restrict__ entries2,
                     const float4* __restrict__ verts4,
                     const float* __restrict__ coefs,
                     const int* __restrict__ bnd,
                     const int* __restrict__ nvpm,
                     double* __restrict__ partial, int V) {
    __shared__ unsigned cnt[BROWS];
    __shared__ unsigned rp[BROWS];     // row run start (absolute in entries2)
    __shared__ unsigned cur[BROWS];    // cursor; == run end after pass 2
    __shared__ unsigned wsum[8];
    __shared__ double sred[512];
    int b = blockIdx.x;
    int t = threadIdx.x;
    unsigned s0 = base[b], s1 = base[b + 1];

    for (int j = t; j < BROWS; j += 512) cnt[j] = 0;
    __syncthreads();
    // pass 1: count rows (1 LDS atomic / entry; read only .x)
    for (unsigned i = s0 + t; i < s1; i += 512) {
        unsigned ex = ((const unsigned*)(entries + i))[0];
        atomicAdd(&cnt[ex >> 21], 1u);
    }
    __syncthreads();
    // exclusive scan of cnt[0..2048) -> rp (absolute offsets), 4 elems/thread
    unsigned a0 = cnt[4 * t + 0], a1 = cnt[4 * t + 1];
    unsigned a2 = cnt[4 * t + 2], a3 = cnt[4 * t + 3];
    unsigned s = a0 + a1 + a2 + a3;
    int lane = t & 63, wave = t >> 6;
    unsigned x = s;
    for (int off = 1; off < 64; off <<= 1) {
        unsigned y = __shfl_up(x, off);
        if (lane >= off) x += y;
    }
    if (lane == 63) wsum[wave] = x;
    __syncthreads();
    unsigned woff = 0;
    for (int w = 0; w < wave; ++w) woff += wsum[w];
    unsigned excl = s0 + woff + x - s;
    rp[4 * t + 0] = excl;              cur[4 * t + 0] = excl;
    rp[4 * t + 1] = excl + a0;         cur[4 * t + 1] = excl + a0;
    rp[4 * t + 2] = excl + a0 + a1;    cur[4 * t + 2] = excl + a0 + a1;
    rp[4 * t + 3] = excl + a0 + a1 + a2; cur[4 * t + 3] = excl + a0 + a1 + a2;
    __syncthreads();
    // pass 2: place entries row-sorted (1 LDS atomic + 8B global write / entry)
    for (unsigned i = s0 + t; i < s1; i += 512) {
        uint2 e = entries[i];
        unsigned p = atomicAdd(&cur[e.x >> 21], 1u);
        entries2[p] = e;
    }
    __syncthreads();   // vmcnt(0) drain + barrier: entries2 visible in-block

    // accumulate + finalize: thread owns rows 4t..4t+3 (contiguous runs ->
    // a wave covers ~256 consecutive rows of entries2: L1/L2-friendly)
    float inv0 = 1.0f / (float)nvpm[0];
    float inv1 = 1.0f / (float)nvpm[1];
    float inv2 = 1.0f / (float)nvpm[2];
    float inv3 = 1.0f / (float)nvpm[3];
    int bd0 = bnd[0], bd1 = bnd[1], bd2 = bnd[2];

    double acc = 0.0;
    int r0 = b << 11;
    #pragma unroll
    for (int q = 0; q < 4; ++q) {
        int j = 4 * t + q;
        int r = r0 + j;
        if (r < V) {
            float sx = 0.f, sy = 0.f, sz = 0.f, sw = 0.f;
            unsigned e0 = rp[j], e1 = cur[j];
            for (unsigned k = e0; k < e1; ++k) {
                uintv2 e = *(const uintv2*)(entries2 + k);
                float4 p = verts4[e.x & 0x1FFFFFu];
                float v = __uint_as_float(e.y);
                sx += v * p.x; sy += v * p.y; sz += v * p.z; sw += v;
            }
            float nw = (sw > 0.0f) ? (1.0f / sw) : sw;
            float4 pv = verts4[r];
            float d0 = sx * nw - pv.x;
            float d1 = sy * nw - pv.y;
            float d2 = sz * nw - pv.z;
            float loss = sqrtf(d0 * d0 + d1 * d1 + d2 * d2);
            float w = (r < bd0) ? inv0 : (r < bd1) ? inv1 : (r < bd2) ? inv2
                                                                      : inv3;
            acc += (double)(loss * w * coefs[r]);
        }
    }

    sred[t] = acc;
    __syncthreads();
    for (int st = 256; st > 0; st >>= 1) {
        if (t < st) sred[t] += sred[t + st];
        __syncthreads();
    }
    if (t == 0) atomicAdd(partial, sred[0]);
}

// R8 bucket kernel (fallback when ws can't fit entries2).
template <bool V4>
__global__ void bucket_kernel(const uint2* __restrict__ entries,
                              const unsigned* __restrict__ base,
                              const float* __restrict__ verts,
                              const float4* __restrict__ verts4,
                              const float* __restrict__ coefs,
                              const int* __restrict__ mesh_idx,
                              const int* __restrict__ nvpm,
                              double* __restrict__ partial, int V) {
    __shared__ float ax[BROWS], ay[BROWS], az[BROWS], aw[BROWS];
    int b = blockIdx.x;
    for (int j = threadIdx.x; j < BROWS; j += blockDim.x) {
        ax[j] = 0.f; ay[j] = 0.f; az[j] = 0.f; aw[j] = 0.f;
    }
    __syncthreads();
    unsigned s0 = base[b], s1 = base[b + 1];

    auto gather3 = [&](unsigned c, float& x, float& y, float& z) {
        if (V4) {
            float4 p = verts4[c];
            x = p.x; y = p.y; z = p.z;
        } else {
            x = verts[3 * c + 0];
            y = verts[3 * c + 1];
            z = verts[3 * c + 2];
        }
    };
    auto atomics = [&](unsigned ex, unsigned ey, float x, float y, float z) {
        unsigned lr = ex >> 21;
        float v = __uint_as_float(ey);
        atomicAdd(&ax[lr], v * x);
        atomicAdd(&ay[lr], v * y);
        atomicAdd(&az[lr], v * z);
        atomicAdd(&aw[lr], v);
    };

    for (unsigned i = s0 + threadIdx.x; i < s1; i += blockDim.x) {
        uint2 e = entries[i];
        float x, y, z;
        gather3(e.x & 0x1FFFFFu, x, y, z);
        atomics(e.x, e.y, x, y, z);
    }
    __syncthreads();

    float inv0 = 1.0f / (float)nvpm[0];
    float inv1 = 1.0f / (float)nvpm[1];
    float inv2 = 1.0f / (float)nvpm[2];
    float inv3 = 1.0f / (float)nvpm[3];

    double acc = 0.0;
    int r0 = b << 11;
    for (int j = threadIdx.x; j < BROWS; j += blockDim.x) {
        int r = r0 + j;
        if (r < V) {
            float rs = aw[j];
            float nw = (rs > 0.0f) ? (1.0f / rs) : rs;
            float vx, vy, vz;
            gather3((unsigned)r, vx, vy, vz);
            float d0 = ax[j] * nw - vx;
            float d1 = ay[j] * nw - vy;
            float d2 = az[j] * nw - vz;
            float loss = sqrtf(d0 * d0 + d1 * d1 + d2 * d2);
            int m = mesh_idx[r];
            float w = (m == 0) ? inv0 : (m == 1) ? inv1 : (m == 2) ? inv2 : inv3;
            acc += (double)(loss * w * coefs[r]);
        }
    }

    __shared__ double sred[512];
    sred[threadIdx.x] = acc;
    __syncthreads();
    for (int s = blockDim.x / 2; s > 0; s >>= 1) {
        if (threadIdx.x < s) sred[threadIdx.x] += sred[threadIdx.x + s];
        __syncthreads();
    }
    if (threadIdx.x == 0) atomicAdd(partial, sred[0]);
}

__global__ void write_out_kernel(const double* __restrict__ partial,
                                 float* __restrict__ out) {
    if (threadIdx.x == 0 && blockIdx.x == 0)
        out[0] = (float)(partial[0] * 0.25);  // / N_MESHES
}

// ---- Fallback path (R1): global-atomic scatter, needs only 64 + 16V ws ----

__global__ void fb_mesh_counts_kernel(const int* __restrict__ mesh_idx, int v,
                                      int* __restrict__ nvpm) {
    int m = threadIdx.x;
    if (m >= 4) return;
    auto lb = [&](int t) {
        int lo = 0, hi = v;
        while (lo < hi) {
            int mid = (lo + hi) >> 1;
            if (mesh_idx[mid] < t) lo = mid + 1; else hi = mid;
        }
        return lo;
    };
    nvpm[m] = lb(m + 1) - lb(m);
}

__global__ void fb_scatter_kernel(const float* __restrict__ verts,
                                  const float* __restrict__ vals,
                                  const int* __restrict__ rows,
                                  const int* __restrict__ cols,
                                  float* __restrict__ acc, int nnz) {
    int i = blockIdx.x * blockDim.x + threadIdx.x;
    if (i >= nnz) return;
    int r = rows[i];
    int c = cols[i];
    float v = vals[i];
    float* p = acc + 4ll * r;
    atomicAdd(p + 0, v * verts[3 * c + 0]);
    atomicAdd(p + 1, v * verts[3 * c + 1]);
    atomicAdd(p + 2, v * verts[3 * c + 2]);
    atomicAdd(p + 3, v);
}

__global__ void fb_finalize_kernel(const float* __restrict__ verts,
                                   const float* __restrict__ coefs,
                                   const int* __restrict__ mesh_idx,
                                   const float4* __restrict__ acc,
                                   const int* __restrict__ nvpm,
                                   double* __restrict__ partial, int v) {
    float inv0 = 1.0f / (float)nvpm[0];
    float inv1 = 1.0f / (float)nvpm[1];
    float inv2 = 1.0f / (float)nvpm[2];
    float inv3 = 1.0f / (float)nvpm[3];
    double acc_sum = 0.0;
    for (int i = blockIdx.x * blockDim.x + threadIdx.x; i < v;
         i += gridDim.x * blockDim.x) {
        float4 a = acc[i];
        float rs = a.w;
        float nw = (rs > 0.0f) ? (1.0f / rs) : rs;
        float r0 = a.x * nw - verts[3 * i + 0];
        float r1 = a.y * nw - verts[3 * i + 1];
        float r2 = a.z * nw - verts[3 * i + 2];
        float loss = sqrtf(r0 * r0 + r1 * r1 + r2 * r2);
        int m = mesh_idx[i];
        float w = (m == 0) ? inv0 : (m == 1) ? inv1 : (m == 2) ? inv2 : inv3;
        acc_sum += (double)(loss * w * coefs[i]);
    }
    __shared__ double sred[256];
    sred[threadIdx.x] = acc_sum;
    __syncthreads();
    for (int s = blockDim.x / 2; s > 0; s >>= 1) {
        if (threadIdx.x < s) sred[threadIdx.x] += sred[threadIdx.x + s];
        __syncthreads();
    }
    if (threadIdx.x == 0) atomicAdd(partial, sred[0]);
}

extern "C" void kernel_launch(void* const* d_in, const int* in_sizes, int n_in,
                              void* d_out, int out_size, void* d_ws, size_t ws_size,
                              hipStream_t stream) {
    const float* verts    = (const float*)d_in[0];
    const float* lap_vals = (const float*)d_in[1];
    const int*   lap_rows = (const int*)d_in[2];
    const int*   lap_cols = (const int*)d_in[3];
    const int*   mesh_idx = (const int*)d_in[4];
    const float* coefs    = (const float*)d_in[5];
    float* out = (float*)d_out;

    const int V   = in_sizes[0] / 3;
    const int NNZ = in_sizes[1];
    const int B   = (V + BROWS - 1) / BROWS;           // 977 for V = 2M
    int cpb = (NNZ + NB - 1) / NB;
    cpb = (cpb + 3) & ~3;                              // mult of 4 for int4

    char* ws = (char*)d_ws;
    const size_t off_hist     = 262144;
    const size_t off_entries  = off_hist + (size_t)BMAX * NB * 2;          // +4MB
    const size_t off_entries2 = off_entries + (size_t)NNZ * 8;
    double*         partial  = (double*)(ws + 0);
    int*            nvpm     = (int*)(ws + 8);
    int*            bnd      = (int*)(ws + 24);
    unsigned*       base     = (unsigned*)(ws + 64);
    unsigned*       total    = (unsigned*)(ws + 16384);
    unsigned short* hist     = (unsigned short*)(ws + off_hist);
    uint2*          entries  = (uint2*)(ws + off_entries);
    uint2*          entries2 = (uint2*)(ws + off_entries2);

    size_t sort_need = off_entries2 + 64;
    size_t v4_need   = off_entries2 + (size_t)16 * V + 64;     // verts4 after entries
    size_t rs_need   = off_entries2 + (size_t)NNZ * 8 + (size_t)16 * V + 64;

    (void)hipMemsetAsync(d_ws, 0, 64, stream);

    if (ws_size >= sort_need && B <= BMAX && V <= (1 << 21)) {
        bool rs  = (ws_size >= rs_need);
        bool v4  = rs || (ws_size >= v4_need);
        float4* verts4 = rs ? (float4*)(ws + off_entries2 + (size_t)NNZ * 8)
                            : (float4*)(ws + off_entries2);
        hist_kernel<<<NB, 256, 0, stream>>>(lap_rows, NNZ, cpb, B, hist,
                                            verts, V, v4 ? verts4 : nullptr);
        scan_blocks_kernel<<<B, 256, 0, stream>>>(hist, total);
        scan_buckets_kernel<<<1, 1024, 0, stream>>>(total, base, B,
                                                    mesh_idx, V, nvpm, bnd);
        scatter_kernel<<<NB, 256, 0, stream>>>(lap_rows, lap_cols, lap_vals,
                                               hist, base, entries, NNZ, cpb, B);
        if (rs) {
            rowsort_accum_kernel<<<B, 512, 0, stream>>>(entries, base, entries2,
                                                        verts4, coefs, bnd,
                                                        nvpm, partial, V);
        } else if (v4) {
            bucket_kernel<true><<<B, 512, 0, stream>>>(
                entries, base, verts, verts4, coefs, mesh_idx, nvpm, partial, V);
        } else {
            bucket_kernel<false><<<B, 512, 0, stream>>>(
                entries, base, verts, verts4, coefs, mesh_idx, nvpm, partial, V);
        }
    } else {
        float* acc = (float*)(ws + 64);
        (void)hipMemsetAsync(ws + 64, 0, (size_t)16 * V, stream);
        fb_mesh_counts_kernel<<<1, 64, 0, stream>>>(mesh_idx, V, nvpm);
        fb_scatter_kernel<<<(NNZ + 255) / 256, 256, 0, stream>>>(
            verts, lap_vals, lap_rows, lap_cols, acc, NNZ);
        fb_finalize_kernel<<<2048, 256, 0, stream>>>(
            verts, coefs, mesh_idx, (const float4*)acc, nvpm, partial, V);
    }

    write_out_kernel<<<1, 64, 0, stream>>>(partial, out);
}

// Round 8
// 680.340 us; speedup vs baseline: 1.5333x; 1.5333x over previous
//
#include <hip/hip_runtime.h>

// LaplaceMeshLoss: COO Laplacian SpMV + per-row norm + weighted scalar reduce.
//
// R13: two-sided bucketing — NO divergent global gathers anywhere.
//   Evidence: bucket accumulate pinned at 312us, invariant to fetched bytes
//   (848/730/201MB), ILP, and L2 residency -> per-CU L1 miss-concurrency
//   (MSHR) limit on divergent 16B/lane gathers (55K lines/CU / (32/300-900cy)
//   ~ 210-312us). R12: machine sustains 3.3TB/s when streaming -> fix is
//   structural: make every random access an LDS read or a plain store.
//   Pipeline:
//     1) hist/scan/scatter by COLUMN bucket (2048 cols) -> entries_c
//     2) hist2/scan: row-bucket counts per col-bucket -> positions
//     3) product_scatter (per col-bucket): verts window -> LDS (coalesced
//        24KB), products via LDS lookups, scatter 16B records to row-bucket
//        positions (plain stores, no atomic returns to wait on)
//     4) accum_finalize (per row-bucket): stream products COALESCED, 4 LDS
//        atomics/entry, fused finalize (verts read coalesced by row)
//   Fallbacks: R8 single-sort path (~117MB ws), then R1 global-atomic path.
//
// ws layout (R13 path):
//   [0,8)        double partial
//   [8,24)       int nvpm[4]
//   [24,40)      int bnd[4]
//   [64,8260)    uint base_c[2049]
//   [8448,16644) uint base_r[2049]
//   [16896,...)  uint total_c[2048]
//   [25088,...)  uint total_r[2048]
//   [262144,+4MB)   ushort hist_c[BMAX*NB]
//   [+4MB)          ushort hist2[BMAX*NB]      (memset 0: tail cols)
//   [+112MB)        uint2  entries_c[NNZ]
//   [+224MB)        float4 prods[NNZ]
//   [+28MB)         ushort rows3[NNZ]

#define NB 1024           // chunk-blocks in hist/scatter; also hist row width
#define BMAX 2048
#define BROWS 2048        // rows (and cols) per bucket -> 11 bits

__global__ void hist_kernel(const int* __restrict__ keys, int nnz, int cpb,
                            int B, unsigned short* __restrict__ hist) {
    __shared__ unsigned h[BMAX];
    for (int b = threadIdx.x; b < B; b += blockDim.x) h[b] = 0;
    __syncthreads();
    int k = blockIdx.x;
    int i0 = k * cpb;
    int i1 = min(i0 + cpb, nnz);
    for (int i = i0 + 4 * (int)threadIdx.x; i < i1; i += 4 * blockDim.x) {
        if (i + 3 < i1) {
            int4 r4 = *(const int4*)(keys + i);
            atomicAdd(&h[r4.x >> 11], 1u);
            atomicAdd(&h[r4.y >> 11], 1u);
            atomicAdd(&h[r4.z >> 11], 1u);
            atomicAdd(&h[r4.w >> 11], 1u);
        } else {
            for (int j = i; j < i1; ++j) atomicAdd(&h[keys[j] >> 11], 1u);
        }
    }
    __syncthreads();
    for (int b = threadIdx.x; b < B; b += blockDim.x)
        hist[(size_t)b * NB + k] = (unsigned short)h[b];
}

// One block per bucket: exclusive scan of hist[b][0..NB) in place (ushort).
__global__ void scan_blocks_kernel(unsigned short* __restrict__ hist,
                                   unsigned* __restrict__ total) {
    int b = blockIdx.x;
    int t = threadIdx.x;            // 256 threads
    int lane = t & 63, wave = t >> 6;
    unsigned short* hp = hist + (size_t)b * NB;
    ushort4 hv = ((const ushort4*)hp)[t];
    unsigned a0 = hv.x, a1 = hv.y, a2 = hv.z, a3 = hv.w;
    unsigned sum = a0 + a1 + a2 + a3;
    unsigned x = sum;
    for (int off = 1; off < 64; off <<= 1) {
        unsigned y = __shfl_up(x, off);
        if (lane >= off) x += y;
    }
    __shared__ unsigned wsum[4];
    if (lane == 63) wsum[wave] = x;
    __syncthreads();
    unsigned woff = 0;
    for (int w = 0; w < wave; ++w) woff += wsum[w];
    unsigned excl = woff + x - sum;
    ushort4 ov;
    ov.x = (unsigned short)excl;
    ov.y = (unsigned short)(excl + a0);
    ov.z = (unsigned short)(excl + a0 + a1);
    ov.w = (unsigned short)(excl + a0 + a1 + a2);
    ((ushort4*)hp)[t] = ov;
    if (t == 255) total[b] = woff + x;
}

__global__ void scan_buckets_kernel(const unsigned* __restrict__ total,
                                    unsigned* __restrict__ base, int B,
                                    const int* __restrict__ mesh_idx, int v,
                                    int* __restrict__ nvpm,
                                    int* __restrict__ bnd) {
    int t = threadIdx.x;            // 1024 threads, 2 elems each
    if (t < 4) {
        auto lb = [&](int tgt) {
            int lo = 0, hi = v;
            while (lo < hi) {
                int mid = (lo + hi) >> 1;
                if (mesh_idx[mid] < tgt) lo = mid + 1; else hi = mid;
            }
            return lo;
        };
        int hi_b = lb(t + 1);
        nvpm[t] = hi_b - lb(t);
        bnd[t]  = hi_b;
    }
    __shared__ unsigned buf0[1024], buf1[1024];
    unsigned x0 = (2 * t < B) ? total[2 * t] : 0u;
    unsigned x1 = (2 * t + 1 < B) ? total[2 * t + 1] : 0u;
    unsigned pair = x0 + x1;
    buf0[t] = pair;
    __syncthreads();
    unsigned* src = buf0;
    unsigned* dst = buf1;
    unsigned vv = pair;
    for (int off = 1; off < 1024; off <<= 1) {
        vv = src[t];
        if (t >= off) vv += src[t - off];
        dst[t] = vv;
        __syncthreads();
        unsigned* tmp = src; src = dst; dst = tmp;
    }
    unsigned excl = vv - pair;
    base[2 * t] = excl;
    base[2 * t + 1] = excl + x0;
    if (t == 1023) base[2048] = vv;
}

// COLMODE: key = cols, payload (colLow<<21)|row (needs V <= 2^21).
// !COLMODE: key = rows, payload (rowLow<<21)|col  (R8 fallback path).
template <bool COLMODE>
__global__ void scatter_kernel(const int* __restrict__ rows,
                               const int* __restrict__ cols,
                               const float* __restrict__ vals,
                               const unsigned short* __restrict__ hist,
                               const unsigned* __restrict__ base,
                               uint2* __restrict__ dst,
                               int nnz, int cpb, int B) {
    __shared__ unsigned cur[BMAX];
    int k = blockIdx.x;
    for (int b = threadIdx.x; b < B; b += blockDim.x)
        cur[b] = base[b] + hist[(size_t)b * NB + k];
    __syncthreads();
    int i0 = k * cpb;
    int i1 = min(i0 + cpb, nnz);
    for (int i = i0 + 4 * (int)threadIdx.x; i < i1; i += 4 * blockDim.x) {
        if (i + 3 < i1) {
            int4   r4 = *(const int4*)(rows + i);
            int4   c4 = *(const int4*)(cols + i);
            float4 v4 = *(const float4*)(vals + i);
            int k0 = COLMODE ? c4.x : r4.x;
            int k1 = COLMODE ? c4.y : r4.y;
            int k2 = COLMODE ? c4.z : r4.z;
            int k3 = COLMODE ? c4.w : r4.w;
            int o0 = COLMODE ? r4.x : c4.x;
            int o1 = COLMODE ? r4.y : c4.y;
            int o2 = COLMODE ? r4.z : c4.z;
            int o3 = COLMODE ? r4.w : c4.w;
            unsigned p0 = atomicAdd(&cur[k0 >> 11], 1u);
            unsigned p1 = atomicAdd(&cur[k1 >> 11], 1u);
            unsigned p2 = atomicAdd(&cur[k2 >> 11], 1u);
            unsigned p3 = atomicAdd(&cur[k3 >> 11], 1u);
            uint2 e0, e1, e2, e3;
            e0.x = ((unsigned)(k0 & (BROWS - 1)) << 21) | (unsigned)o0;
            e0.y = __float_as_uint(v4.x);
            e1.x = ((unsigned)(k1 & (BROWS - 1)) << 21) | (unsigned)o1;
            e1.y = __float_as_uint(v4.y);
            e2.x = ((unsigned)(k2 & (BROWS - 1)) << 21) | (unsigned)o2;
            e2.y = __float_as_uint(v4.z);
            e3.x = ((unsigned)(k3 & (BROWS - 1)) << 21) | (unsigned)o3;
            e3.y = __float_as_uint(v4.w);
            dst[p0] = e0;
            dst[p1] = e1;
            dst[p2] = e2;
            dst[p3] = e3;
        } else {
            for (int j = i; j < i1; ++j) {
                int kk = COLMODE ? cols[j] : rows[j];
                int oo = COLMODE ? rows[j] : cols[j];
                unsigned p = atomicAdd(&cur[kk >> 11], 1u);
                uint2 e;
                e.x = ((unsigned)(kk & (BROWS - 1)) << 21) | (unsigned)oo;
                e.y = __float_as_uint(vals[j]);
                dst[p] = e;
            }
        }
    }
}

// One block per col-bucket: histogram the ROW-buckets of its segment into
// hist2 column bc (hist2 pre-zeroed for tail columns).
__global__ void hist2_kernel(const uint2* __restrict__ entries_c,
                             const unsigned* __restrict__ base_c,
                             unsigned short* __restrict__ hist2, int B_r) {
    __shared__ unsigned h[BMAX];
    int bc = blockIdx.x;
    for (int b = threadIdx.x; b < B_r; b += blockDim.x) h[b] = 0;
    __syncthreads();
    unsigned s0 = base_c[bc], s1 = base_c[bc + 1];
    for (unsigned i = s0 + threadIdx.x; i < s1; i += blockDim.x) {
        uint2 e = entries_c[i];
        atomicAdd(&h[(e.x & 0x1FFFFFu) >> 11], 1u);
    }
    __syncthreads();
    for (int b = threadIdx.x; b < B_r; b += blockDim.x)
        hist2[(size_t)b * NB + bc] = (unsigned short)h[b];
}

// One block per col-bucket: verts window -> LDS (coalesced), products via LDS
// lookups, scatter 16B records + 2B rowLow to row-bucket positions.
__global__ void __launch_bounds__(512)
product_scatter_kernel(const uint2* __restrict__ entries_c,
                       const unsigned* __restrict__ base_c,
                       const unsigned short* __restrict__ hist2,
                       const unsigned* __restrict__ base_r,
                       const float* __restrict__ verts, int V, int B_r,
                       float4* __restrict__ prods,
                       unsigned short* __restrict__ rows3) {
    __shared__ float wbuf[3 * BROWS];     // 24KB vertex window
    __shared__ unsigned cur2[BMAX];       // 8KB cursors
    int bc = blockIdx.x;
    int c0 = bc << 11;
    int nfl = 3 * min(BROWS, V - c0);
    for (int j = threadIdx.x; j < nfl; j += blockDim.x)
        wbuf[j] = verts[3 * c0 + j];
    for (int b = threadIdx.x; b < B_r; b += blockDim.x)
        cur2[b] = base_r[b] + hist2[(size_t)b * NB + bc];
    __syncthreads();
    unsigned s0 = base_c[bc], s1 = base_c[bc + 1];
    for (unsigned i = s0 + threadIdx.x; i < s1; i += blockDim.x) {
        uint2 e = entries_c[i];
        unsigned colLow = e.x >> 21;
        unsigned row    = e.x & 0x1FFFFFu;
        float v = __uint_as_float(e.y);
        float x = wbuf[3 * colLow + 0];
        float y = wbuf[3 * colLow + 1];
        float z = wbuf[3 * colLow + 2];
        unsigned p = atomicAdd(&cur2[row >> 11], 1u);
        prods[p] = make_float4(v * x, v * y, v * z, v);
        rows3[p] = (unsigned short)(row & (BROWS - 1));
    }
}

// One block per row-bucket: stream products COALESCED, 4 LDS atomics/entry,
// fused finalize (verts read coalesced by consecutive rows).
__global__ void __launch_bounds__(512)
accum_finalize_kernel(const float4* __restrict__ prods,
                      const unsigned short* __restrict__ rows3,
                      const unsigned* __restrict__ base_r,
                      const float* __restrict__ verts,
                      const float* __restrict__ coefs,
                      const int* __restrict__ bnd,
                      const int* __restrict__ nvpm,
                      double* __restrict__ partial, int V) {
    __shared__ float ax[BROWS], ay[BROWS], az[BROWS], aw[BROWS];
    __shared__ double sred[512];
    int b = blockIdx.x;
    int t = threadIdx.x;
    for (int j = t; j < BROWS; j += blockDim.x) {
        ax[j] = 0.f; ay[j] = 0.f; az[j] = 0.f; aw[j] = 0.f;
    }
    __syncthreads();
    unsigned s0 = base_r[b], s1 = base_r[b + 1];
    for (unsigned i = s0 + t; i < s1; i += blockDim.x) {
        float4 p = prods[i];
        unsigned lr = rows3[i];
        atomicAdd(&ax[lr], p.x);
        atomicAdd(&ay[lr], p.y);
        atomicAdd(&az[lr], p.z);
        atomicAdd(&aw[lr], p.w);
    }
    __syncthreads();

    float inv0 = 1.0f / (float)nvpm[0];
    float inv1 = 1.0f / (float)nvpm[1];
    float inv2 = 1.0f / (float)nvpm[2];
    float inv3 = 1.0f / (float)nvpm[3];
    int bd0 = bnd[0], bd1 = bnd[1], bd2 = bnd[2];

    double acc = 0.0;
    int r0 = b << 11;
    for (int j = t; j < BROWS; j += blockDim.x) {
        int r = r0 + j;
        if (r < V) {
            float rs = aw[j];
            float nw = (rs > 0.0f) ? (1.0f / rs) : rs;
            float d0 = ax[j] * nw - verts[3 * r + 0];
            float d1 = ay[j] * nw - verts[3 * r + 1];
            float d2 = az[j] * nw - verts[3 * r + 2];
            float loss = sqrtf(d0 * d0 + d1 * d1 + d2 * d2);
            float w = (r < bd0) ? inv0 : (r < bd1) ? inv1 : (r < bd2) ? inv2
                                                                      : inv3;
            acc += (double)(loss * w * coefs[r]);
        }
    }

    sred[t] = acc;
    __syncthreads();
    for (int st = 256; st > 0; st >>= 1) {
        if (t < st) sred[t] += sred[t + st];
        __syncthreads();
    }
    if (t == 0) atomicAdd(partial, sred[0]);
}

// R8 fallback bucket kernel (raw verts gathers + LDS atomics).
__global__ void bucket_kernel(const uint2* __restrict__ entries,
                              const unsigned* __restrict__ base,
                              const float* __restrict__ verts,
                              const float* __restrict__ coefs,
                              const int* __restrict__ bnd,
                              const int* __restrict__ nvpm,
                              double* __restrict__ partial, int V) {
    __shared__ float ax[BROWS], ay[BROWS], az[BROWS], aw[BROWS];
    int b = blockIdx.x;
    for (int j = threadIdx.x; j < BROWS; j += blockDim.x) {
        ax[j] = 0.f; ay[j] = 0.f; az[j] = 0.f; aw[j] = 0.f;
    }
    __syncthreads();
    unsigned s0 = base[b], s1 = base[b + 1];
    for (unsigned i = s0 + threadIdx.x; i < s1; i += blockDim.x) {
        uint2 e = entries[i];
        unsigned lr = e.x >> 21;
        unsigned c  = e.x & 0x1FFFFFu;
        float v = __uint_as_float(e.y);
        float x = verts[3 * c + 0];
        float y = verts[3 * c + 1];
        float z = verts[3 * c + 2];
        atomicAdd(&ax[lr], v * x);
        atomicAdd(&ay[lr], v * y);
        atomicAdd(&az[lr], v * z);
        atomicAdd(&aw[lr], v);
    }
    __syncthreads();

    float inv0 = 1.0f / (float)nvpm[0];
    float inv1 = 1.0f / (float)nvpm[1];
    float inv2 = 1.0f / (float)nvpm[2];
    float inv3 = 1.0f / (float)nvpm[3];
    int bd0 = bnd[0], bd1 = bnd[1], bd2 = bnd[2];

    double acc = 0.0;
    int r0 = b << 11;
    for (int j = threadIdx.x; j < BROWS; j += blockDim.x) {
        int r = r0 + j;
        if (r < V) {
            float rs = aw[j];
            float nw = (rs > 0.0f) ? (1.0f / rs) : rs;
            float d0 = ax[j] * nw - verts[3 * r + 0];
            float d1 = ay[j] * nw - verts[3 * r + 1];
            float d2 = az[j] * nw - verts[3 * r + 2];
            float loss = sqrtf(d0 * d0 + d1 * d1 + d2 * d2);
            float w = (r < bd0) ? inv0 : (r < bd1) ? inv1 : (r < bd2) ? inv2
                                                                      : inv3;
            acc += (double)(loss * w * coefs[r]);
        }
    }

    __shared__ double sred[512];
    sred[threadIdx.x] = acc;
    __syncthreads();
    for (int s = blockDim.x / 2; s > 0; s >>= 1) {
        if (threadIdx.x < s) sred[threadIdx.x] += sred[threadIdx.x + s];
        __syncthreads();
    }
    if (threadIdx.x == 0) atomicAdd(partial, sred[0]);
}

__global__ void write_out_kernel(const double* __restrict__ partial,
                                 float* __restrict__ out) {
    if (threadIdx.x == 0 && blockIdx.x == 0)
        out[0] = (float)(partial[0] * 0.25);  // / N_MESHES
}

// ---- Fallback path (R1): global-atomic scatter, needs only 64 + 16V ws ----

__global__ void fb_mesh_counts_kernel(const int* __restrict__ mesh_idx, int v,
                                      int* __restrict__ nvpm) {
    int m = threadIdx.x;
    if (m >= 4) return;
    auto lb = [&](int t) {
        int lo = 0, hi = v;
        while (lo < hi) {
            int mid = (lo + hi) >> 1;
            if (mesh_idx[mid] < t) lo = mid + 1; else hi = mid;
        }
        return lo;
    };
    nvpm[m] = lb(m + 1) - lb(m);
}

__global__ void fb_scatter_kernel(const float* __restrict__ verts,
                                  const float* __restrict__ vals,
                                  const int* __restrict__ rows,
                                  const int* __restrict__ cols,
                                  float* __restrict__ acc, int nnz) {
    int i = blockIdx.x * blockDim.x + threadIdx.x;
    if (i >= nnz) return;
    int r = rows[i];
    int c = cols[i];
    float v = vals[i];
    float* p = acc + 4ll * r;
    atomicAdd(p + 0, v * verts[3 * c + 0]);
    atomicAdd(p + 1, v * verts[3 * c + 1]);
    atomicAdd(p + 2, v * verts[3 * c + 2]);
    atomicAdd(p + 3, v);
}

__global__ void fb_finalize_kernel(const float* __restrict__ verts,
                                   const float* __restrict__ coefs,
                                   const int* __restrict__ mesh_idx,
                                   const float4* __restrict__ acc,
                                   const int* __restrict__ nvpm,
                                   double* __restrict__ partial, int v) {
    float inv0 = 1.0f / (float)nvpm[0];
    float inv1 = 1.0f / (float)nvpm[1];
    float inv2 = 1.0f / (float)nvpm[2];
    float inv3 = 1.0f / (float)nvpm[3];
    double acc_sum = 0.0;
    for (int i = blockIdx.x * blockDim.x + threadIdx.x; i < v;
         i += gridDim.x * blockDim.x) {
        float4 a = acc[i];
        float rs = a.w;
        float nw = (rs > 0.0f) ? (1.0f / rs) : rs;
        float r0 = a.x * nw - verts[3 * i + 0];
        float r1 = a.y * nw - verts[3 * i + 1];
        float r2 = a.z * nw - verts[3 * i + 2];
        float loss = sqrtf(r0 * r0 + r1 * r1 + r2 * r2);
        int m = mesh_idx[i];
        float w = (m == 0) ? inv0 : (m == 1) ? inv1 : (m == 2) ? inv2 : inv3;
        acc_sum += (double)(loss * w * coefs[i]);
    }
    __shared__ double sred[256];
    sred[threadIdx.x] = acc_sum;
    __syncthreads();
    for (int s = blockDim.x / 2; s > 0; s >>= 1) {
        if (threadIdx.x < s) sred[threadIdx.x] += sred[threadIdx.x + s];
        __syncthreads();
    }
    if (threadIdx.x == 0) atomicAdd(partial, sred[0]);
}

extern "C" void kernel_launch(void* const* d_in, const int* in_sizes, int n_in,
                              void* d_out, int out_size, void* d_ws, size_t ws_size,
                              hipStream_t stream) {
    const float* verts    = (const float*)d_in[0];
    const float* lap_vals = (const float*)d_in[1];
    const int*   lap_rows = (const int*)d_in[2];
    const int*   lap_cols = (const int*)d_in[3];
    const int*   mesh_idx = (const int*)d_in[4];
    const float* coefs    = (const float*)d_in[5];
    float* out = (float*)d_out;

    const int V   = in_sizes[0] / 3;
    const int NNZ = in_sizes[1];
    const int B   = (V + BROWS - 1) / BROWS;   // row- AND col-buckets (977)
    int cpb = (NNZ + NB - 1) / NB;
    cpb = (cpb + 3) & ~3;

    char* ws = (char*)d_ws;
    const size_t off_histc   = 262144;
    const size_t off_hist2   = off_histc + (size_t)BMAX * NB * 2;       // +4MB
    const size_t off_entries = off_hist2 + (size_t)BMAX * NB * 2;       // +4MB
    const size_t off_prods   = off_entries + (size_t)NNZ * 8;
    const size_t off_rows3   = off_prods + (size_t)NNZ * 16;
    double*         partial  = (double*)(ws + 0);
    int*            nvpm     = (int*)(ws + 8);
    int*            bnd      = (int*)(ws + 24);
    unsigned*       base_c   = (unsigned*)(ws + 64);
    unsigned*       base_r   = (unsigned*)(ws + 8448);
    unsigned*       total_c  = (unsigned*)(ws + 16896);
    unsigned*       total_r  = (unsigned*)(ws + 25088);
    unsigned short* hist_c   = (unsigned short*)(ws + off_histc);
    unsigned short* hist2    = (unsigned short*)(ws + off_hist2);
    uint2*          entries  = (uint2*)(ws + off_entries);
    float4*         prods    = (float4*)(ws + off_prods);
    unsigned short* rows3    = (unsigned short*)(ws + off_rows3);

    size_t r13_need  = off_rows3 + (size_t)NNZ * 2 + 64;
    size_t sort_need = off_entries + (size_t)NNZ * 8 + 64;

    (void)hipMemsetAsync(d_ws, 0, 64, stream);

    bool ok_pack = (V <= (1 << 21)) && (B <= NB) && (B <= BMAX);
    if (ws_size >= r13_need && ok_pack) {
        (void)hipMemsetAsync(ws + off_hist2, 0, (size_t)BMAX * NB * 2, stream);
        // col phase
        hist_kernel<<<NB, 256, 0, stream>>>(lap_cols, NNZ, cpb, B, hist_c);
        scan_blocks_kernel<<<B, 256, 0, stream>>>(hist_c, total_c);
        scan_buckets_kernel<<<1, 1024, 0, stream>>>(total_c, base_c, B,
                                                    mesh_idx, V, nvpm, bnd);
        scatter_kernel<true><<<NB, 256, 0, stream>>>(
            lap_rows, lap_cols, lap_vals, hist_c, base_c, entries, NNZ, cpb, B);
        // row positions for products
        hist2_kernel<<<B, 512, 0, stream>>>(entries, base_c, hist2, B);
        scan_blocks_kernel<<<B, 256, 0, stream>>>(hist2, total_r);
        scan_buckets_kernel<<<1, 1024, 0, stream>>>(total_r, base_r, B,
                                                    mesh_idx, V, nvpm, bnd);
        // products via LDS window, scatter to row-bucket order
        product_scatter_kernel<<<B, 512, 0, stream>>>(
            entries, base_c, hist2, base_r, verts, V, B, prods, rows3);
        // coalesced accumulate + fused finalize
        accum_finalize_kernel<<<B, 512, 0, stream>>>(
            prods, rows3, base_r, verts, coefs, bnd, nvpm, partial, V);
    } else if (ws_size >= sort_need && ok_pack) {
        // R8 fallback: single row-sort + gather bucket kernel
        hist_kernel<<<NB, 256, 0, stream>>>(lap_rows, NNZ, cpb, B, hist_c);
        scan_blocks_kernel<<<B, 256, 0, stream>>>(hist_c, total_c);
        scan_buckets_kernel<<<1, 1024, 0, stream>>>(total_c, base_c, B,
                                                    mesh_idx, V, nvpm, bnd);
        scatter_kernel<false><<<NB, 256, 0, stream>>>(
            lap_rows, lap_cols, lap_vals, hist_c, base_c, entries, NNZ, cpb, B);
        bucket_kernel<<<B, 512, 0, stream>>>(entries, base_c, verts, coefs,
                                             bnd, nvpm, partial, V);
    } else {
        float* acc = (float*)(ws + 64);
        (void)hipMemsetAsync(ws + 64, 0, (size_t)16 * V, stream);
        fb_mesh_counts_kernel<<<1, 64, 0, stream>>>(mesh_idx, V, nvpm);
        fb_scatter_kernel<<<(NNZ + 255) / 256, 256, 0, stream>>>(
            verts, lap_vals, lap_rows, lap_cols, acc, NNZ);
        fb_finalize_kernel<<<2048, 256, 0, stream>>>(
            verts, coefs, mesh_idx, (const float4*)acc, nvpm, partial, V);
    }

    write_out_kernel<<<1, 64, 0, stream>>>(partial, out);
}